// Round 1
// baseline (242.337 us; speedup 1.0000x reference)
//
#include <hip/hip_runtime.h>

#define POOLSZ 7
#define NROIS  128
#define IMG_H  28
#define IMG_W  28
#define IMG_C  512
#define WINDOW 4
// total ROIs across batch-reshape: 16*128 = 2048
#define TOT_ROIS 2048
// threads: one per float4 channel group
#define C4 (IMG_C / 4)          // 128
#define TOT_POS (TOT_ROIS * POOLSZ * POOLSZ)   // 100352

__global__ __launch_bounds__(256)
void roi_crop_resize_kernel(const float* __restrict__ img,
                            const float* __restrict__ rois,
                            float* __restrict__ out) {
    int t = blockIdx.x * 256 + threadIdx.x;
    int c4  = t & (C4 - 1);     // channel float4 group 0..127
    int pos = t >> 7;           // n*49 + py*7 + px
    if (pos >= TOT_POS) return;

    int px  = pos % POOLSZ;
    int tmp = pos / POOLSZ;
    int py  = tmp % POOLSZ;
    int n   = tmp / POOLSZ;

    // boxes: x1 = col3, y1 = col4 of the flattened (N,5) rois
    float x1 = rois[n * 5 + 3];
    float y1 = rois[n * 5 + 4];
    // replicate reference arithmetic order exactly
    float x2 = x1 + (float)WINDOW / (float)IMG_W;
    float y2 = y1 + (float)WINDOW / (float)IMG_H;

    const float Hm1 = (float)(IMG_H - 1);   // 27
    const float Wm1 = (float)(IMG_W - 1);   // 27
    float ys = y1 * Hm1 + (float)py * ((y2 - y1) * Hm1 / (float)(POOLSZ - 1));
    float xs = x1 * Wm1 + (float)px * ((x2 - x1) * Wm1 / (float)(POOLSZ - 1));

    float y0f = floorf(ys);
    float x0f = floorf(xs);
    float ly = ys - y0f;
    float lx = xs - x0f;

    int y0  = (int)fminf(fmaxf(y0f,       0.f), Hm1);
    int y1i = (int)fminf(fmaxf(y0f + 1.f, 0.f), Hm1);
    int x0  = (int)fminf(fmaxf(x0f,       0.f), Wm1);
    int x1i = (int)fminf(fmaxf(x0f + 1.f, 0.f), Wm1);

    float m = ((ys >= 0.f) & (ys <= Hm1) & (xs >= 0.f) & (xs <= Wm1)) ? 1.f : 0.f;

    const float4* img4 = (const float4*)img;   // only img[0] is used
    float4 tl = img4[(y0  * IMG_W + x0 ) * C4 + c4];
    float4 tr = img4[(y0  * IMG_W + x1i) * C4 + c4];
    float4 bl = img4[(y1i * IMG_W + x0 ) * C4 + c4];
    float4 br = img4[(y1i * IMG_W + x1i) * C4 + c4];

    float omly = 1.f - ly;
    float4 v;
    v.x = ((tl.x + (tr.x - tl.x) * lx) * omly + (bl.x + (br.x - bl.x) * lx) * ly) * m;
    v.y = ((tl.y + (tr.y - tl.y) * lx) * omly + (bl.y + (br.y - bl.y) * lx) * ly) * m;
    v.z = ((tl.z + (tr.z - tl.z) * lx) * omly + (bl.z + (br.z - bl.z) * lx) * ly) * m;
    v.w = ((tl.w + (tr.w - tl.w) * lx) * omly + (bl.w + (br.w - bl.w) * lx) * ly) * m;

    ((float4*)out)[pos * C4 + c4] = v;
}

extern "C" void kernel_launch(void* const* d_in, const int* in_sizes, int n_in,
                              void* d_out, int out_size, void* d_ws, size_t ws_size,
                              hipStream_t stream) {
    const float* img  = (const float*)d_in[0];
    const float* rois = (const float*)d_in[1];
    float* out = (float*)d_out;

    // total threads = TOT_POS * C4 = 100352 * 128 = 12,845,056 ; block = 256
    long long total = (long long)TOT_POS * C4;
    int grid = (int)((total + 255) / 256);
    roi_crop_resize_kernel<<<grid, 256, 0, stream>>>(img, rois, out);
}

// Round 3
// 239.195 us; speedup vs baseline: 1.0131x; 1.0131x over previous
//
#include <hip/hip_runtime.h>

#define POOLSZ 7
#define NROIS  128
#define IMG_H  28
#define IMG_W  28
#define IMG_C  512
#define WINDOW 4
// total ROIs across batch-reshape: 16*128 = 2048
#define TOT_ROIS 2048
// threads: one per float4 channel group
#define C4 (IMG_C / 4)          // 128
#define TOT_POS (TOT_ROIS * POOLSZ * POOLSZ)   // 100352

typedef float f4 __attribute__((ext_vector_type(4)));   // native vector: OK for nontemporal builtins

__global__ __launch_bounds__(256)
void roi_crop_resize_kernel(const float* __restrict__ img,
                            const float* __restrict__ rois,
                            float* __restrict__ out) {
    int t = blockIdx.x * 256 + threadIdx.x;
    int c4  = t & (C4 - 1);     // channel float4 group 0..127
    int pos = t >> 7;           // n*49 + py*7 + px
    if (pos >= TOT_POS) return;

    int px  = pos % POOLSZ;
    int tmp = pos / POOLSZ;
    int py  = tmp % POOLSZ;
    int n   = tmp / POOLSZ;

    // boxes: x1 = col3, y1 = col4 of the flattened (N,5) rois
    float x1 = rois[n * 5 + 3];
    float y1 = rois[n * 5 + 4];
    // replicate reference arithmetic order exactly
    float x2 = x1 + (float)WINDOW / (float)IMG_W;
    float y2 = y1 + (float)WINDOW / (float)IMG_H;

    const float Hm1 = (float)(IMG_H - 1);   // 27
    const float Wm1 = (float)(IMG_W - 1);   // 27
    float ys = y1 * Hm1 + (float)py * ((y2 - y1) * Hm1 / (float)(POOLSZ - 1));
    float xs = x1 * Wm1 + (float)px * ((x2 - x1) * Wm1 / (float)(POOLSZ - 1));

    float y0f = floorf(ys);
    float x0f = floorf(xs);
    float ly = ys - y0f;
    float lx = xs - x0f;

    int y0  = (int)fminf(fmaxf(y0f,       0.f), Hm1);
    int y1i = (int)fminf(fmaxf(y0f + 1.f, 0.f), Hm1);
    int x0  = (int)fminf(fmaxf(x0f,       0.f), Wm1);
    int x1i = (int)fminf(fmaxf(x0f + 1.f, 0.f), Wm1);

    float m = ((ys >= 0.f) & (ys <= Hm1) & (xs >= 0.f) & (xs <= Wm1)) ? 1.f : 0.f;

    const f4* img4 = (const f4*)img;   // only img[0] is used
    f4 tl = img4[(y0  * IMG_W + x0 ) * C4 + c4];
    f4 tr = img4[(y0  * IMG_W + x1i) * C4 + c4];
    f4 bl = img4[(y1i * IMG_W + x0 ) * C4 + c4];
    f4 br = img4[(y1i * IMG_W + x1i) * C4 + c4];

    float omly = 1.f - ly;
    f4 v = ((tl + (tr - tl) * lx) * omly + (bl + (br - bl) * lx) * ly) * m;

    // Non-temporal: keep the 205 MB write stream from evicting the 1.6 MB
    // image out of the per-XCD L2 (write-pollution was the round-0 theory).
    __builtin_nontemporal_store(v, ((f4*)out) + pos * C4 + c4);
}

extern "C" void kernel_launch(void* const* d_in, const int* in_sizes, int n_in,
                              void* d_out, int out_size, void* d_ws, size_t ws_size,
                              hipStream_t stream) {
    const float* img  = (const float*)d_in[0];
    const float* rois = (const float*)d_in[1];
    float* out = (float*)d_out;

    // total threads = TOT_POS * C4 = 100352 * 128 = 12,845,056 ; block = 256
    long long total = (long long)TOT_POS * C4;
    int grid = (int)((total + 255) / 256);
    roi_crop_resize_kernel<<<grid, 256, 0, stream>>>(img, rois, out);
}

// Round 4
// 216.753 us; speedup vs baseline: 1.1180x; 1.1035x over previous
//
#include <hip/hip_runtime.h>

#define POOLSZ 7
#define IMG_H  28
#define IMG_W  28
#define IMG_C  512
#define C4     128            // float4 groups per pixel (512/4)
#define SLICES 4              // channel slices per ROI
#define SC4    (C4 / SLICES)  // 32 float4 per slice
#define TOT_ROIS 2048         // 16 * 128 from the reshape
#define PATCH  6              // 7x7 samples span <4 px -> 6x6 patch suffices

typedef float f4 __attribute__((ext_vector_type(4)));

__global__ __launch_bounds__(256)
void roi_crop_resize_lds(const float* __restrict__ img,
                         const float* __restrict__ rois,
                         float* __restrict__ out) {
    // 6*6 pixels * 32 f4 * 16 B = 18432 B -> 8 blocks/CU (full occupancy)
    __shared__ f4 lds[PATCH * PATCH * SC4];

    int n     = blockIdx.x >> 2;      // ROI id 0..2047
    int slice = blockIdx.x & 3;       // channel slice 0..3

    // boxes: x1 = col3, y1 = col4 of flattened (N,5) rois; both in [0,1)
    float x1 = rois[n * 5 + 3];
    float y1 = rois[n * 5 + 4];
    // replicate reference arithmetic order exactly
    float x2 = x1 + 4.0f / 28.0f;
    float y2 = y1 + 4.0f / 28.0f;
    const float Hm1 = 27.0f, Wm1 = 27.0f;
    float dy  = (y2 - y1) * Hm1 / 6.0f;   // ((y2-y1)*27)/6, same assoc as ref
    float dx  = (x2 - x1) * Wm1 / 6.0f;
    float ys0 = y1 * Hm1;                 // >= 0 always (y1 in [0,1))
    float xs0 = x1 * Wm1;

    int Y0 = (int)floorf(ys0); if (Y0 > 27) Y0 = 27; if (Y0 < 0) Y0 = 0;
    int X0 = (int)floorf(xs0); if (X0 > 27) X0 = 27; if (X0 < 0) X0 = 0;

    const f4* img4 = (const f4*)img;   // only img[0] is used
    int tid = threadIdx.x;

    // ---- stage 6x6 patch (rows/cols clamped to 27) for this channel slice ----
    for (int i = tid; i < PATCH * PATCH * SC4; i += 256) {
        int c   = i & (SC4 - 1);
        int pix = i >> 5;                       // 0..35
        int ry  = Y0 + pix / PATCH; if (ry > 27) ry = 27;
        int rx  = X0 + pix % PATCH; if (rx > 27) rx = 27;
        lds[i] = img4[(ry * IMG_W + rx) * C4 + slice * SC4 + c];
    }
    __syncthreads();

    // ---- compute 49 positions x 32 f4 from LDS ----
    f4* out4 = (f4*)out;
    for (int i = tid; i < 49 * SC4; i += 256) {
        int c  = i & (SC4 - 1);
        int p  = i >> 5;                        // 0..48
        int py = p / POOLSZ, px = p % POOLSZ;

        float ys = ys0 + (float)py * dy;
        float xs = xs0 + (float)px * dx;
        float y0f = floorf(ys), x0f = floorf(xs);
        float ly = ys - y0f, lx = xs - x0f;
        int y0  = (int)fminf(fmaxf(y0f,       0.f), Hm1);
        int y1i = (int)fminf(fmaxf(y0f + 1.f, 0.f), Hm1);
        int x0  = (int)fminf(fmaxf(x0f,       0.f), Wm1);
        int x1i = (int)fminf(fmaxf(x0f + 1.f, 0.f), Wm1);
        float m = ((ys >= 0.f) & (ys <= Hm1) & (xs >= 0.f) & (xs <= Wm1)) ? 1.f : 0.f;

        // LDS patch indices — provably in [0,5]: window span 6*dy < 4 px,
        // floor(ys)>=Y0 since ys>=ys0>=0, clamps are monotone.
        int ry0 = y0  - Y0, ry1 = y1i - Y0;
        int rx0 = x0  - X0, rx1 = x1i - X0;
        f4 tl = lds[(ry0 * PATCH + rx0) * SC4 + c];
        f4 tr = lds[(ry0 * PATCH + rx1) * SC4 + c];
        f4 bl = lds[(ry1 * PATCH + rx0) * SC4 + c];
        f4 br = lds[(ry1 * PATCH + rx1) * SC4 + c];

        float omly = 1.f - ly;
        f4 v = ((tl + (tr - tl) * lx) * omly + (bl + (br - bl) * lx) * ly) * m;

        int pos = n * 49 + p;
        __builtin_nontemporal_store(v, out4 + pos * C4 + slice * SC4 + c);
    }
}

extern "C" void kernel_launch(void* const* d_in, const int* in_sizes, int n_in,
                              void* d_out, int out_size, void* d_ws, size_t ws_size,
                              hipStream_t stream) {
    const float* img  = (const float*)d_in[0];
    const float* rois = (const float*)d_in[1];
    float* out = (float*)d_out;

    // 2048 ROIs x 4 channel slices
    roi_crop_resize_lds<<<TOT_ROIS * SLICES, 256, 0, stream>>>(img, rois, out);
}